// Round 14
// baseline (163.501 us; speedup 1.0000x reference)
//
#include <hip/hip_runtime.h>
#include <hip/hip_bf16.h>

typedef __attribute__((ext_vector_type(4))) float f32x4;
typedef __attribute__((ext_vector_type(8))) short s16x8;
typedef __attribute__((ext_vector_type(4))) unsigned short u16x4;
typedef __attribute__((ext_vector_type(8))) __bf16 bf16x8;

#define HDIM 512
#define SEQ  2048
#define NB   64
#define BM   32
#define NBLK ((NB * SEQ) / BM)   // 4096 blocks
#define CPB  (SEQ / BM)          // 64 chunks per batch

// round-to-nearest-even fp32 -> bf16 bits
static __device__ __forceinline__ unsigned short f2bf(float f) {
  unsigned u = __float_as_uint(f);
  u += 0x7fffu + ((u >> 16) & 1u);
  return (unsigned short)(u >> 16);
}
static __device__ __forceinline__ float bf2f(unsigned short v) {
  return __uint_as_float(((unsigned)v) << 16);
}

static __device__ __forceinline__ f32x4 mfma16(s16x8 a, s16x8 b, f32x4 c) {
  return __builtin_amdgcn_mfma_f32_16x16x32_bf16(
      __builtin_bit_cast(bf16x8, a), __builtin_bit_cast(bf16x8, b), c, 0, 0, 0);
}

// 4 B-fragment loads for one k-step: SGPR base sp, shared voffset, imm per nf.
#define BLOADG(dst, sp)                                                        \
  do {                                                                         \
    asm volatile("global_load_dwordx4 %0, %1, %2 offset:0"                     \
                 : "=&v"((dst)[0]) : "v"(voff), "s"(sp));                      \
    asm volatile("global_load_dwordx4 %0, %1, %2 offset:1024"                  \
                 : "=&v"((dst)[1]) : "v"(voff), "s"(sp));                      \
    asm volatile("global_load_dwordx4 %0, %1, %2 offset:2048"                  \
                 : "=&v"((dst)[2]) : "v"(voff), "s"(sp));                      \
    asm volatile("global_load_dwordx4 %0, %1, %2 offset:3072"                  \
                 : "=&v"((dst)[3]) : "v"(voff), "s"(sp));                      \
  } while (0)

// one A staging load (16B fp32 per thread); this thread's slice j (j=0..7).
// SGPR base is BLOCK-uniform only (encblk + j*64 floats); the tid-dependent
// parity offset lives in the VGPR offset aoff (R13 fix: sparity in "s" base
// made the operand non-uniform -> VGPR pair -> invalid operand).
#define SLOAD(dst, j)                                                          \
  asm volatile("global_load_dwordx4 %0, %1, %2"                                \
               : "=&v"(dst) : "v"(aoff), "s"(encblk + (j) * 64))

#define WAITV(N)                                                               \
  do {                                                                         \
    asm volatile("s_waitcnt vmcnt(%0)" :: "i"(N) : "memory");                  \
    __builtin_amdgcn_sched_barrier(0);                                         \
  } while (0)

// pack+write staged slice (s = 2j+sparity) into the swizzled A tile (row r)
#define PACKW(src, j)                                                          \
  do {                                                                         \
    u16x4 pk;                                                                  \
    pk.x = f2bf((src).x); pk.y = f2bf((src).y);                                \
    pk.z = f2bf((src).z); pk.w = f2bf((src).w);                                \
    *(u16x4*)((char*)Asm + r * 1024 +                                          \
              ((((2 * (j) + sparity) * 4 + (h >> 1)) ^ r7) * 16) +             \
              (h & 1) * 8) = pk;                                               \
  } while (0)

// ---------------- kernel 0: fused W1-convert + zproj -------------------------
__global__ void prep(const float* __restrict__ w1, unsigned short* __restrict__ o,
                     const float* __restrict__ dec, const float* __restrict__ W2,
                     const float* __restrict__ b1, const float* __restrict__ b2,
                     float* __restrict__ zfull) {
  const int bx = blockIdx.x, tid = threadIdx.x;
  if (bx < 128) {
    int id = bx * 256 + tid;   // 32768 chunks of 16B
    int kk = id >> 11, n = (id >> 2) & 511, r4 = id & 3;
    const float* src = w1 + (long)n * HDIM + kk * 32 + r4 * 8;
    f32x4 v0 = *(const f32x4*)src;
    f32x4 v1 = *(const f32x4*)(src + 4);
    u16x4 a, b;
    a.x = f2bf(v0.x); a.y = f2bf(v0.y); a.z = f2bf(v0.z); a.w = f2bf(v0.w);
    b.x = f2bf(v1.x); b.y = f2bf(v1.y); b.z = f2bf(v1.z); b.w = f2bf(v1.w);
    unsigned short* dst = o + (long)id * 8;
    *(u16x4*)dst = a;
    *(u16x4*)(dst + 4) = b;
  } else {
    const int idx = bx - 128;
    const int b = idx >> 1, oc = idx & 1;
    const int oo = oc * 256 + tid;
    __shared__ float d_s[HDIM];
    d_s[tid] = dec[b * HDIM + tid];
    d_s[tid + 256] = dec[b * HDIM + tid + 256];
    __syncthreads();
    const float* w = W2 + (long)oo * HDIM;
    float s = 0.f;
#pragma unroll 4
    for (int k = 0; k < HDIM; k += 4) {
      f32x4 v = *(const f32x4*)(w + k);
      s += v.x * d_s[k] + v.y * d_s[k + 1] + v.z * d_s[k + 2] + v.w * d_s[k + 3];
    }
    zfull[b * HDIM + oo] = s + b1[oo] + b2[oo];
  }
}

// ------ kernel 1: fused GEMM + tanh + V-dot + local softmax + partial ctx ----
// BM=32, LDS ~33 KB, acc 32 AGPR: 3 blocks/CU = 24 waves/CU (75% occupancy).
// K-loop is R9's proven wave-rotated depth-1 staircase, mf reduced to 2.
__global__ __launch_bounds__(512, 6)
void gemm_fused(const float* __restrict__ enc, const unsigned short* __restrict__ w1k,
                const float* __restrict__ zfull, const float* __restrict__ V,
                const float* __restrict__ bv, float* __restrict__ scores,
                unsigned short* __restrict__ pctx, float* __restrict__ ml) {
  __shared__ __align__(16) char pool[33920];
  unsigned short* Asm = (unsigned short*)pool;            // 32 KiB bf16 tile
  float* red  = (float*)(pool + 32768);                   // 8*32 f
  float* plds = (float*)(pool + 33792);                   // 32 f
  float* pcr  = (float*)pool;                             // overlays A after reads

  const int tid = threadIdx.x;
  const int wid = tid >> 6;
  const int lane = tid & 63;
  const long m0 = (long)blockIdx.x * BM;
  const int b = (int)(m0 >> 11);

  const int r4 = lane >> 4, c15 = lane & 15, c7 = c15 & 7;
  const char* Ab = (const char*)Asm;
  const unsigned voff = (unsigned)((wid * 64 + c15) * 64 + r4 * 16);
  const int widu = __builtin_amdgcn_readfirstlane(wid);

  // staging addressing: 256-thread parity groups; r=row(0..31), h=chunk(0..7)
  const int sparity = tid >> 8;            // waves 0-3 -> even, 4-7 -> odd slices
  const int idx = tid & 255;
  const int r = idx >> 3, h = idx & 7, r7 = r & 7;
  const float* encblk = enc + m0 * HDIM;
  const unsigned aoff = (unsigned)(r * 2048 + h * 16 + sparity * 128);

  // ---- prologue: 8 slices per thread (slices 2j+sparity), 8-deep queue ----
  {
    f32x4 pa, pb, pc, pd, pe, pf, pg, ph;
    SLOAD(pa, 0); SLOAD(pb, 1); SLOAD(pc, 2); SLOAD(pd, 3);
    SLOAD(pe, 4); SLOAD(pf, 5); SLOAD(pg, 6); SLOAD(ph, 7);
    WAITV(4);
    PACKW(pa, 0); PACKW(pb, 1); PACKW(pc, 2); PACKW(pd, 3);
    WAITV(0);
    PACKW(pe, 4); PACKW(pf, 5); PACKW(pg, 6); PACKW(ph, 7);
  }
  __syncthreads();   // A tile visible; vm queue clean

  f32x4 acc[2][4] = {};
  s16x8 bX[4], bY[4];

  // prefetch this wave's first (rotated) k-step
  BLOADG(bX, w1k + ((widu & 15) * 16384));

  // ---- K-loop: barrier-free, wave-rotated, nf-major vmcnt staircase ----
#pragma unroll
  for (int kk = 0; kk < 16; ++kk) {
    const int ke = (kk + widu) & 15;
    s16x8* cur = (kk & 1) ? bY : bX;
    s16x8* nxt = (kk & 1) ? bX : bY;

    s16x8 af[2];
    const int abase = c15 * 1024 + (((ke * 4 + r4) ^ c7) * 16);
#pragma unroll
    for (int mf = 0; mf < 2; ++mf)
      af[mf] = *(const s16x8*)(Ab + abase + mf * 16384);

    if (kk < 15)
      BLOADG(nxt, w1k + ((((kk + 1) + widu) & 15) * 16384));

    __builtin_amdgcn_s_setprio(1);
    if (kk < 15) {
      WAITV(7);
      acc[0][0] = mfma16(af[0], cur[0], acc[0][0]);
      acc[1][0] = mfma16(af[1], cur[0], acc[1][0]);
      WAITV(6);
      acc[0][1] = mfma16(af[0], cur[1], acc[0][1]);
      acc[1][1] = mfma16(af[1], cur[1], acc[1][1]);
      WAITV(5);
      acc[0][2] = mfma16(af[0], cur[2], acc[0][2]);
      acc[1][2] = mfma16(af[1], cur[2], acc[1][2]);
      WAITV(4);
      acc[0][3] = mfma16(af[0], cur[3], acc[0][3]);
      acc[1][3] = mfma16(af[1], cur[3], acc[1][3]);
    } else {
      WAITV(3);
      acc[0][0] = mfma16(af[0], cur[0], acc[0][0]);
      acc[1][0] = mfma16(af[1], cur[0], acc[1][0]);
      WAITV(2);
      acc[0][1] = mfma16(af[0], cur[1], acc[0][1]);
      acc[1][1] = mfma16(af[1], cur[1], acc[1][1]);
      WAITV(1);
      acc[0][2] = mfma16(af[0], cur[2], acc[0][2]);
      acc[1][2] = mfma16(af[1], cur[2], acc[1][2]);
      WAITV(0);
      acc[0][3] = mfma16(af[0], cur[3], acc[0][3]);
      acc[1][3] = mfma16(af[1], cur[3], acc[1][3]);
    }
    __builtin_amdgcn_s_setprio(0);
  }

  // ---- epilogue 1: scores partials: sum_n tanh(acc + z[n]) * V[n] ----
  // C/D layout (16x16x32): col = lane&15, row = (lane>>4)*4 + j   [m89/m91]
  float zr[4], vr[4];
#pragma unroll
  for (int nf = 0; nf < 4; ++nf) {
    const int n = wid * 64 + nf * 16 + c15;
    zr[nf] = zfull[b * HDIM + n];
    vr[nf] = V[n];
  }
#pragma unroll
  for (int mf = 0; mf < 2; ++mf) {
#pragma unroll
    for (int j = 0; j < 4; ++j) {
      float s = 0.f;
#pragma unroll
      for (int nf = 0; nf < 4; ++nf) {
        float x = acc[mf][nf][j] + zr[nf];
        float e = __expf(2.f * x);
        float t = 1.f - 2.f * __builtin_amdgcn_rcpf(e + 1.f);  // tanh(x)
        s += t * vr[nf];
      }
      s += __shfl_xor(s, 1); s += __shfl_xor(s, 2);
      s += __shfl_xor(s, 4); s += __shfl_xor(s, 8);
      if (c15 == 0) red[wid * BM + mf * 16 + r4 * 4 + j] = s;
    }
  }
  __syncthreads();

  // ---- epilogue 2: lanes 0..31 of wave 0 finish scores + softmax stats ----
  if (tid < BM) {
    float s = 0.f;
#pragma unroll
    for (int w = 0; w < 8; ++w) s += red[w * BM + tid];
    s += bv[0];
    scores[m0 + tid] = s;                       // raw score
    float mc = s;
    mc = fmaxf(mc, __shfl_xor(mc, 1));  mc = fmaxf(mc, __shfl_xor(mc, 2));
    mc = fmaxf(mc, __shfl_xor(mc, 4));  mc = fmaxf(mc, __shfl_xor(mc, 8));
    mc = fmaxf(mc, __shfl_xor(mc, 16));
    float p = __expf(s - mc);
    plds[tid] = p;
    float lc = p;
    lc += __shfl_xor(lc, 1); lc += __shfl_xor(lc, 2);
    lc += __shfl_xor(lc, 4); lc += __shfl_xor(lc, 8);
    lc += __shfl_xor(lc, 16);
    if (tid == 0) { ml[blockIdx.x * 2] = mc; ml[blockIdx.x * 2 + 1] = lc; }
  }
  __syncthreads();

  // ---- epilogue 3: pctx[h] = sum_s p[s]*A[s][h]; wave wid does 4 rows ----
  float c8[8] = {};
#pragma unroll
  for (int rr = 0; rr < 4; ++rr) {
    const int rw = wid * 4 + rr;
    s16x8 v = *(const s16x8*)(Ab + rw * 1024 + ((lane ^ (rw & 7)) * 16));
    const float p = plds[rw];
#pragma unroll
    for (int e = 0; e < 8; ++e)
      c8[e] += p * bf2f((unsigned short)v[e]);
  }
  __syncthreads();   // all A reads done; safe to overlay pcr on A region
  {
    f32x4 w0, w1;
    w0.x = c8[0]; w0.y = c8[1]; w0.z = c8[2]; w0.w = c8[3];
    w1.x = c8[4]; w1.y = c8[5]; w1.z = c8[6]; w1.w = c8[7];
    *(f32x4*)((char*)pcr + wid * 2048 + lane * 32) = w0;
    *(f32x4*)((char*)pcr + wid * 2048 + lane * 32 + 16) = w1;
  }
  __syncthreads();
  {
    float s = 0.f;
#pragma unroll
    for (int g = 0; g < 8; ++g) s += pcr[g * 512 + tid];
    pctx[(long)blockIdx.x * HDIM + tid] = f2bf(s);
  }
}

// ---------------- kernel 2: combine partials -> attn (in place) + ctx --------
__global__ void combine(float* __restrict__ attn, const unsigned short* __restrict__ pctx,
                        const float* __restrict__ ml, float* __restrict__ ctx) {
  const int b = blockIdx.x, tid = threadIdx.x;   // 512 threads
  const int lane = tid & 63;
  // CPB == 64: one full wave of chunk stats
  float m = ml[(b * CPB + lane) * 2];
  float l = ml[(b * CPB + lane) * 2 + 1];
  float M = m;
#pragma unroll
  for (int off = 1; off < 64; off <<= 1) M = fmaxf(M, __shfl_xor(M, off));
  float le = l * __expf(m - M);
  float L = le;
#pragma unroll
  for (int off = 1; off < 64; off <<= 1) L += __shfl_xor(L, off);
  const float invL = 1.f / L;

  __shared__ float wc[CPB];
  if (tid < CPB) wc[tid] = __expf(ml[(b * CPB + tid) * 2] - M) * invL;

  // attn rescale in place: attn currently holds raw scores
  float sv[4];
#pragma unroll
  for (int i = 0; i < 4; ++i) sv[i] = attn[(long)b * SEQ + i * 512 + tid];
#pragma unroll
  for (int i = 0; i < 4; ++i)
    attn[(long)b * SEQ + i * 512 + tid] = __expf(sv[i] - M) * invL;

  __syncthreads();
  // ctx[h] = sum_c pctx[c][h] * wc[c]
  float a = 0.f;
#pragma unroll 8
  for (int c = 0; c < CPB; ++c)
    a += bf2f(pctx[(long)(b * CPB + c) * HDIM + tid]) * wc[c];
  ctx[(long)b * HDIM + tid] = a;
}

extern "C" void kernel_launch(void* const* d_in, const int* in_sizes, int n_in,
                              void* d_out, int out_size, void* d_ws, size_t ws_size,
                              hipStream_t stream) {
  const float* enc = (const float*)d_in[0];
  const float* dec = (const float*)d_in[1];
  const float* W1  = (const float*)d_in[2];
  const float* b1  = (const float*)d_in[3];
  const float* W2  = (const float*)d_in[4];
  const float* b2  = (const float*)d_in[5];
  const float* V   = (const float*)d_in[6];
  const float* bv  = (const float*)d_in[7];

  float* out  = (float*)d_out;
  float* ctx  = out;                       // 64*512
  float* attn = out + NB * HDIM;           // 64*2048 (raw scores first, rescaled in place)

  char* ws = (char*)d_ws;
  unsigned short* w1k  = (unsigned short*)ws;                   // 512 KiB (k-step-major)
  float*          zful = (float*)(ws + 524288);                 // 128 KiB
  unsigned short* pctx = (unsigned short*)(ws + 655360);        // 4 MiB (4096*512 bf16)
  float*          mlb  = (float*)(ws + 4849664);                // 32 KiB (4096*2 f32)
  (void)in_sizes; (void)n_in; (void)out_size; (void)ws_size;

  prep<<<256, 256, 0, stream>>>(W1, w1k, dec, W2, b1, b2, zful);
  gemm_fused<<<NBLK, 512, 0, stream>>>(enc, w1k, zful, V, bv, attn, pctx, mlb);
  combine<<<NB, 512, 0, stream>>>(attn, pctx, mlb, ctx);
}

// Round 15
// 118.096 us; speedup vs baseline: 1.3845x; 1.3845x over previous
//
#include <hip/hip_runtime.h>
#include <hip/hip_bf16.h>

typedef __attribute__((ext_vector_type(4))) float f32x4;
typedef __attribute__((ext_vector_type(8))) short s16x8;
typedef __attribute__((ext_vector_type(4))) unsigned short u16x4;
typedef __attribute__((ext_vector_type(8))) __bf16 bf16x8;

#define HDIM 512
#define SEQ  2048
#define NB   64
#define BM   64
#define NBLK ((NB * SEQ) / BM)   // 2048 blocks
#define CPB  (SEQ / BM)          // 32 chunks per batch

// round-to-nearest-even fp32 -> bf16 bits
static __device__ __forceinline__ unsigned short f2bf(float f) {
  unsigned u = __float_as_uint(f);
  u += 0x7fffu + ((u >> 16) & 1u);
  return (unsigned short)(u >> 16);
}
static __device__ __forceinline__ float bf2f(unsigned short v) {
  return __uint_as_float(((unsigned)v) << 16);
}

static __device__ __forceinline__ f32x4 mfma16(s16x8 a, s16x8 b, f32x4 c) {
  return __builtin_amdgcn_mfma_f32_16x16x32_bf16(
      __builtin_bit_cast(bf16x8, a), __builtin_bit_cast(bf16x8, b), c, 0, 0, 0);
}

// 4 B-fragment loads for one k-step: SGPR base sp, shared voffset, imm per nf.
// NO wave rotation (R15): all waves + both co-resident blocks walk k-steps in
// the same order -> trailing block's loads hit leading block's L1 lines.
#define BLOADG(dst, sp)                                                        \
  do {                                                                         \
    asm volatile("global_load_dwordx4 %0, %1, %2 offset:0"                     \
                 : "=&v"((dst)[0]) : "v"(voff), "s"(sp));                      \
    asm volatile("global_load_dwordx4 %0, %1, %2 offset:1024"                  \
                 : "=&v"((dst)[1]) : "v"(voff), "s"(sp));                      \
    asm volatile("global_load_dwordx4 %0, %1, %2 offset:2048"                  \
                 : "=&v"((dst)[2]) : "v"(voff), "s"(sp));                      \
    asm volatile("global_load_dwordx4 %0, %1, %2 offset:3072"                  \
                 : "=&v"((dst)[3]) : "v"(voff), "s"(sp));                      \
  } while (0)

// one A-slice staging load (16B fp32 per thread) for slice s
#define SLOAD(dst, s)                                                          \
  asm volatile("global_load_dwordx4 %0, %1, %2"                                \
               : "=&v"(dst) : "v"(aoff), "s"(encblk + (s) * 32))

#define WAITV(N)                                                               \
  do {                                                                         \
    asm volatile("s_waitcnt vmcnt(%0)" :: "i"(N) : "memory");                  \
    __builtin_amdgcn_sched_barrier(0);                                         \
  } while (0)

// pack+write one staged slice s into the swizzled A tile
#define PACKW(src, s)                                                          \
  do {                                                                         \
    u16x4 pk;                                                                  \
    pk.x = f2bf((src).x); pk.y = f2bf((src).y);                                \
    pk.z = f2bf((src).z); pk.w = f2bf((src).w);                                \
    *(u16x4*)((char*)Asm + wrow * 1024 +                                       \
              (((((s) * 4) + (wc >> 1)) ^ wr7) * 16) + (wc & 1) * 8) = pk;     \
  } while (0)

// ---------------- kernel 0: fused W1-convert + zproj -------------------------
__global__ void prep(const float* __restrict__ w1, unsigned short* __restrict__ o,
                     const float* __restrict__ dec, const float* __restrict__ W2,
                     const float* __restrict__ b1, const float* __restrict__ b2,
                     float* __restrict__ zfull) {
  const int bx = blockIdx.x, tid = threadIdx.x;
  if (bx < 128) {
    int id = bx * 256 + tid;   // 32768 chunks of 16B
    int kk = id >> 11, n = (id >> 2) & 511, r4 = id & 3;
    const float* src = w1 + (long)n * HDIM + kk * 32 + r4 * 8;
    f32x4 v0 = *(const f32x4*)src;
    f32x4 v1 = *(const f32x4*)(src + 4);
    u16x4 a, b;
    a.x = f2bf(v0.x); a.y = f2bf(v0.y); a.z = f2bf(v0.z); a.w = f2bf(v0.w);
    b.x = f2bf(v1.x); b.y = f2bf(v1.y); b.z = f2bf(v1.z); b.w = f2bf(v1.w);
    unsigned short* dst = o + (long)id * 8;
    *(u16x4*)dst = a;
    *(u16x4*)(dst + 4) = b;
  } else {
    const int idx = bx - 128;
    const int b = idx >> 1, oc = idx & 1;
    const int oo = oc * 256 + tid;
    __shared__ float d_s[HDIM];
    d_s[tid] = dec[b * HDIM + tid];
    d_s[tid + 256] = dec[b * HDIM + tid + 256];
    __syncthreads();
    const float* w = W2 + (long)oo * HDIM;
    float s = 0.f;
#pragma unroll 4
    for (int k = 0; k < HDIM; k += 4) {
      f32x4 v = *(const f32x4*)(w + k);
      s += v.x * d_s[k] + v.y * d_s[k + 1] + v.z * d_s[k + 2] + v.w * d_s[k + 3];
    }
    zfull[b * HDIM + oo] = s + b1[oo] + b2[oo];
  }
}

// ------ kernel 1: fused GEMM + tanh + V-dot + local softmax + partial ctx ----
// R9 structure, minus wave k-rotation (L1 line sharing between the two
// co-resident lockstep blocks), plus early B(k0) prefetch in the prologue.
__global__ __launch_bounds__(512, 4)
void gemm_fused(const float* __restrict__ enc, const unsigned short* __restrict__ w1k,
                const float* __restrict__ zfull, const float* __restrict__ V,
                const float* __restrict__ bv, float* __restrict__ scores,
                unsigned short* __restrict__ pctx, float* __restrict__ ml) {
  __shared__ __align__(16) char pool[67840];
  unsigned short* Asm = (unsigned short*)pool;            // 64 KiB bf16 tile
  float* red  = (float*)(pool + 65536);                   // 8*64 f
  float* plds = (float*)(pool + 67584);                   // 64 f
  float* pcr  = (float*)pool;                             // overlays A after reads

  const int tid = threadIdx.x;
  const int wid = tid >> 6;
  const int lane = tid & 63;
  const long m0 = (long)blockIdx.x * BM;
  const int b = (int)(m0 >> 11);

  const int r4 = lane >> 4, c15 = lane & 15, c7 = c15 & 7;
  const char* Ab = (const char*)Asm;
  const unsigned voff = (unsigned)((wid * 64 + c15) * 64 + r4 * 16);

  // staging addressing: row = tid>>3, 16B-f32 chunk wc = tid&7
  const int wrow = tid >> 3, wc = tid & 7, wr7 = wrow & 7;
  const float* encblk = enc + m0 * HDIM;
  const unsigned aoff = (unsigned)(wrow * 2048 + wc * 16);

  f32x4 acc[4][4] = {};
  s16x8 bX[4], bY[4];

  // ---- prologue: stage 16 A slices (8 outstanding) + early B(k0) issue ----
  {
    f32x4 pa, pb, pc, pd, pe, pf, pg, ph;
    SLOAD(pa, 0); SLOAD(pb, 1); SLOAD(pc, 2); SLOAD(pd, 3);
    SLOAD(pe, 4); SLOAD(pf, 5); SLOAD(pg, 6); SLOAD(ph, 7);
    WAITV(4);
    PACKW(pa, 0); PACKW(pb, 1); PACKW(pc, 2); PACKW(pd, 3);
    SLOAD(pa, 8); SLOAD(pb, 9); SLOAD(pc, 10); SLOAD(pd, 11);
    WAITV(4);
    PACKW(pe, 4); PACKW(pf, 5); PACKW(pg, 6); PACKW(ph, 7);
    SLOAD(pe, 12); SLOAD(pf, 13); SLOAD(pg, 14); SLOAD(ph, 15);
    BLOADG(bX, w1k);                 // B(k0) drains under the pack/barrier
    WAITV(8);                        // slices 8-11 done (12-15 + B in flight)
    PACKW(pa, 8); PACKW(pb, 9); PACKW(pc, 10); PACKW(pd, 11);
    WAITV(4);                        // slices 12-15 done (B in flight)
    PACKW(pe, 12); PACKW(pf, 13); PACKW(pg, 14); PACKW(ph, 15);
  }
  __syncthreads();   // A tile visible; drains B(k0) too

  // ---- K-loop: barrier-free, un-rotated, nf-major vmcnt staircase ----
#pragma unroll
  for (int kk = 0; kk < 16; ++kk) {
    s16x8* cur = (kk & 1) ? bY : bX;
    s16x8* nxt = (kk & 1) ? bX : bY;

    s16x8 af[4];
    const int abase = c15 * 1024 + (((kk * 4 + r4) ^ c7) * 16);
#pragma unroll
    for (int mf = 0; mf < 4; ++mf)
      af[mf] = *(const s16x8*)(Ab + abase + mf * 16384);

    if (kk < 15)
      BLOADG(nxt, w1k + (kk + 1) * 16384);

    __builtin_amdgcn_s_setprio(1);
    if (kk < 15) {
      WAITV(7);
#pragma unroll
      for (int mf = 0; mf < 4; ++mf) acc[mf][0] = mfma16(af[mf], cur[0], acc[mf][0]);
      WAITV(6);
#pragma unroll
      for (int mf = 0; mf < 4; ++mf) acc[mf][1] = mfma16(af[mf], cur[1], acc[mf][1]);
      WAITV(5);
#pragma unroll
      for (int mf = 0; mf < 4; ++mf) acc[mf][2] = mfma16(af[mf], cur[2], acc[mf][2]);
      WAITV(4);
#pragma unroll
      for (int mf = 0; mf < 4; ++mf) acc[mf][3] = mfma16(af[mf], cur[3], acc[mf][3]);
    } else {
      WAITV(3);
#pragma unroll
      for (int mf = 0; mf < 4; ++mf) acc[mf][0] = mfma16(af[mf], cur[0], acc[mf][0]);
      WAITV(2);
#pragma unroll
      for (int mf = 0; mf < 4; ++mf) acc[mf][1] = mfma16(af[mf], cur[1], acc[mf][1]);
      WAITV(1);
#pragma unroll
      for (int mf = 0; mf < 4; ++mf) acc[mf][2] = mfma16(af[mf], cur[2], acc[mf][2]);
      WAITV(0);
#pragma unroll
      for (int mf = 0; mf < 4; ++mf) acc[mf][3] = mfma16(af[mf], cur[3], acc[mf][3]);
    }
    __builtin_amdgcn_s_setprio(0);
  }

  // ---- epilogue 1: scores[m] = sum_n tanh(acc + z[n]) * V[n] + bv ----
  // C/D layout (16x16x32): col = lane&15, row = (lane>>4)*4 + j   [m89/m91]
  float zr[4], vr[4];
#pragma unroll
  for (int nf = 0; nf < 4; ++nf) {
    const int n = wid * 64 + nf * 16 + c15;
    zr[nf] = zfull[b * HDIM + n];
    vr[nf] = V[n];
  }
#pragma unroll
  for (int mf = 0; mf < 4; ++mf) {
#pragma unroll
    for (int j = 0; j < 4; ++j) {
      float s = 0.f;
#pragma unroll
      for (int nf = 0; nf < 4; ++nf) {
        float x = acc[mf][nf][j] + zr[nf];
        float e = __expf(2.f * x);
        float t = 1.f - 2.f * __builtin_amdgcn_rcpf(e + 1.f);  // tanh(x)
        s += t * vr[nf];
      }
      s += __shfl_xor(s, 1); s += __shfl_xor(s, 2);
      s += __shfl_xor(s, 4); s += __shfl_xor(s, 8);
      if (c15 == 0) red[wid * BM + mf * 16 + r4 * 4 + j] = s;
    }
  }
  __syncthreads();

  // ---- epilogue 2: wave 0 finishes scores + local softmax stats ----
  if (tid < BM) {
    float s = 0.f;
#pragma unroll
    for (int w = 0; w < 8; ++w) s += red[w * BM + tid];
    s += bv[0];
    scores[m0 + tid] = s;                       // raw score
    float mc = s;
#pragma unroll
    for (int off = 1; off < 64; off <<= 1) mc = fmaxf(mc, __shfl_xor(mc, off));
    float p = __expf(s - mc);
    plds[tid] = p;
    float lc = p;
#pragma unroll
    for (int off = 1; off < 64; off <<= 1) lc += __shfl_xor(lc, off);
    if (tid == 0) { ml[blockIdx.x * 2] = mc; ml[blockIdx.x * 2 + 1] = lc; }
  }
  __syncthreads();

  // ---- epilogue 3: pctx[h] = sum_s p[s]*A[s][h], vector LDS reads ----
  float c8[8] = {};
#pragma unroll
  for (int rr = 0; rr < 8; ++rr) {
    const int r = wid * 8 + rr;
    s16x8 v = *(const s16x8*)(Ab + r * 1024 + ((lane ^ rr) * 16));
    const float p = plds[r];
#pragma unroll
    for (int e = 0; e < 8; ++e)
      c8[e] += p * bf2f((unsigned short)v[e]);
  }
  __syncthreads();   // all A reads done; safe to overlay pcr on A region
  {
    f32x4 w0, w1;
    w0.x = c8[0]; w0.y = c8[1]; w0.z = c8[2]; w0.w = c8[3];
    w1.x = c8[4]; w1.y = c8[5]; w1.z = c8[6]; w1.w = c8[7];
    *(f32x4*)((char*)pcr + wid * 2048 + lane * 32) = w0;
    *(f32x4*)((char*)pcr + wid * 2048 + lane * 32 + 16) = w1;
  }
  __syncthreads();
  {
    float s = 0.f;
#pragma unroll
    for (int g = 0; g < 8; ++g) s += pcr[g * 512 + tid];
    pctx[(long)blockIdx.x * HDIM + tid] = f2bf(s);
  }
}

// ---------------- kernel 2: combine partials -> attn (in place) + ctx --------
__global__ void combine(float* __restrict__ attn, const unsigned short* __restrict__ pctx,
                        const float* __restrict__ ml, float* __restrict__ ctx) {
  const int b = blockIdx.x, tid = threadIdx.x;   // 512 threads
  const int lane = tid & 63;
  float m = -1e30f, l = 0.f;
  if (lane < CPB) {
    m = ml[(b * CPB + lane) * 2];
    l = ml[(b * CPB + lane) * 2 + 1];
  }
  float M = m;
#pragma unroll
  for (int off = 1; off < 64; off <<= 1) M = fmaxf(M, __shfl_xor(M, off));
  float le = (lane < CPB) ? l * __expf(m - M) : 0.f;
  float L = le;
#pragma unroll
  for (int off = 1; off < 64; off <<= 1) L += __shfl_xor(L, off);
  const float invL = 1.f / L;

  __shared__ float wc[CPB];
  if (tid < CPB) wc[tid] = __expf(ml[(b * CPB + tid) * 2] - M) * invL;

  // attn rescale in place: attn currently holds raw scores
  float sv[4];
#pragma unroll
  for (int i = 0; i < 4; ++i) sv[i] = attn[(long)b * SEQ + i * 512 + tid];
#pragma unroll
  for (int i = 0; i < 4; ++i)
    attn[(long)b * SEQ + i * 512 + tid] = __expf(sv[i] - M) * invL;

  __syncthreads();
  // ctx[h] = sum_c pctx[c][h] * wc[c]
  float a = 0.f;
#pragma unroll 8
  for (int c = 0; c < CPB; ++c)
    a += bf2f(pctx[(long)(b * CPB + c) * HDIM + tid]) * wc[c];
  ctx[(long)b * HDIM + tid] = a;
}

extern "C" void kernel_launch(void* const* d_in, const int* in_sizes, int n_in,
                              void* d_out, int out_size, void* d_ws, size_t ws_size,
                              hipStream_t stream) {
  const float* enc = (const float*)d_in[0];
  const float* dec = (const float*)d_in[1];
  const float* W1  = (const float*)d_in[2];
  const float* b1  = (const float*)d_in[3];
  const float* W2  = (const float*)d_in[4];
  const float* b2  = (const float*)d_in[5];
  const float* V   = (const float*)d_in[6];
  const float* bv  = (const float*)d_in[7];

  float* out  = (float*)d_out;
  float* ctx  = out;                       // 64*512
  float* attn = out + NB * HDIM;           // 64*2048 (raw scores first, rescaled in place)

  char* ws = (char*)d_ws;
  unsigned short* w1k  = (unsigned short*)ws;                   // 512 KiB (k-step-major)
  float*          zful = (float*)(ws + 524288);                 // 128 KiB
  unsigned short* pctx = (unsigned short*)(ws + 655360);        // 2 MiB (2048*512 bf16)
  float*          mlb  = (float*)(ws + 2752512);                // 16 KiB (2048*2 f32)
  (void)in_sizes; (void)n_in; (void)out_size; (void)ws_size;

  prep<<<256, 256, 0, stream>>>(W1, w1k, dec, W2, b1, b2, zful);
  gemm_fused<<<NBLK, 512, 0, stream>>>(enc, w1k, zful, V, bv, attn, pctx, mlb);
  combine<<<NB, 512, 0, stream>>>(attn, pctx, mlb, ctx);
}